// Round 6
// baseline (213.404 us; speedup 1.0000x reference)
//
#include <hip/hip_runtime.h>
#include <hip/hip_fp16.h>

// GCN: h1 = relu(Agg(x@W1)+b1); h2 = relu(Agg(h1@W2)+b2); out = mean(h2)@Wc+bc
// norm(r,c)=dinv[r]*dinv[c] factors: GEMM epilogue prescales rows by dinv[r],
// agg sums rows, scales by dinv[c] at the end.
// R1: agg MLP (88->57). R2-R4: scattered global atomics/fences: avoid.
// R5-R10: bucket CSR, zero-atomic build, MFMA gemms, parallel scatter (230).
// R11: deeper agg ILP (acc splitting) — neutral. R12: fp8 gather rows.
// R13: split tail k_pool + k_final (210).
// R14/R15: agg+gemm2 fusion dead (213/230): agg tolerates zero added work.
// R16: R13 structure + pk_add (208.6). Aggs NOT VALU-bound.
// R17: half-row two-pass = 260.9; FETCH unchanged -> L2-capacity theory dead.
// R18: fp8 hact + reg-staged colscan (206.96). Best so far.
// R19: (this round) agg latency-concurrency attack: aggs run at ~1TB/s miss
//      service with NO saturated pipe (VALU 34%, L2/L3 line rates ~30x under
//      capability) => latency x concurrency bound. Old loop kept only 4
//      gathers in flight/wave. New shape: 8 slots x 8 lanes x uint4 (full
//      128B row per slot-group), issue-then-consume full unroll => up to 64
//      rows in flight/wave. Same bytes, same math (reassociated). Also
//      HB 128->64 (halves hist/colscan/scatter-table traffic).

typedef _Float16 half8 __attribute__((ext_vector_type(8)));
typedef float f32x4 __attribute__((ext_vector_type(4)));
typedef float f32x2 __attribute__((ext_vector_type(2)));

constexpr int N = 50000;
constexpr int E = 800000;
constexpr int D = 128;
constexpr int DOUT = 40;
constexpr int CAP = 64;               // slots/node (Poisson(16) tail ~1e-18)
constexpr int HB = 64;                // histogram chunks
constexpr int EPB = E / HB;           // 12500 edges/chunk
constexpr int HWRD = 12500;           // 50000 bytes = 12500 words
constexpr int GM = (N + 127) / 128;   // 391 gemm blocks
constexpr int NW = N / 4;             // 12500 agg blocks
constexpr int GF = 3 * GM;            // 1173 = 782 scatter + 391 gemm

// ---------------- Phase A: chunk histograms + per-edge rank + W transpose ---
__global__ __launch_bounds__(1024) void k_hist(const int* __restrict__ col,
                                               unsigned char* __restrict__ hist,
                                               unsigned char* __restrict__ rank,
                                               const float* __restrict__ W1,
                                               const float* __restrict__ W2,
                                               __half* __restrict__ T1,
                                               __half* __restrict__ T2) {
    __shared__ unsigned int h[HWRD];
    int b = blockIdx.x, t = threadIdx.x;
    if (b >= HB) {                        // 32 spare blocks: Wt[n][k]=fp16(W[k][n])
        int o = (b - HB) * 1024 + t;      // 0..32767
        const float* W = (o < 16384) ? W1 : W2;
        __half* T = (o < 16384) ? T1 : T2;
        int oo = o & 16383;
        int n = oo >> 7, k = oo & 127;
        T[oo] = (__half)W[k * 128 + n];
        return;
    }
    for (int i = t; i < HWRD; i += 1024) h[i] = 0;
    __syncthreads();
    int e0 = b * EPB;
    for (int e = e0 + t; e < e0 + EPB; e += 1024) {
        int c = col[e];
        unsigned int old = atomicAdd(&h[c >> 2], 1u << ((c & 3) * 8));
        rank[e] = (unsigned char)((old >> ((c & 3) * 8)) & 0xff);
    }
    __syncthreads();
    unsigned int* out = (unsigned int*)(hist + (size_t)b * 50000);
    for (int i = t; i < HWRD; i += 1024) out[i] = h[i];
}

// ---------------- Phase B: per-node prefix over chunks; deg + dinv ---------
// SWAR dwords (4 nodes/word, deg<=255 so no cross-byte carry). 4 threads per
// column, each scans 16 chunks into registers; LDS-combine quarter sums.
__global__ __launch_bounds__(256) void k_colscan(unsigned char* __restrict__ hist,
                                                 int* __restrict__ deg,
                                                 float* __restrict__ dinv) {
    __shared__ unsigned int part[4][64];
    unsigned int* hw = (unsigned int*)hist;
    int c4 = blockIdx.x * 64 + (threadIdx.x & 63);
    int qq = threadIdx.x >> 6;            // chunk quarter 0..3
    bool ok = c4 < HWRD;
    unsigned int v[16];
    unsigned int s = 0;
    if (ok) {
#pragma unroll
        for (int i = 0; i < 16; ++i) v[i] = hw[(size_t)(qq * 16 + i) * HWRD + c4];
#pragma unroll
        for (int i = 0; i < 16; ++i) s += v[i];
    }
    part[qq][threadIdx.x & 63] = s;
    __syncthreads();
    unsigned int base = 0;
    for (int k = 0; k < qq; ++k) base += part[k][threadIdx.x & 63];
    if (ok) {
        unsigned int run = base;
#pragma unroll
        for (int i = 0; i < 16; ++i) {
            hw[(size_t)(qq * 16 + i) * HWRD + c4] = run;   // exclusive prefix
            run += v[i];
        }
        if (qq == 3) {                    // run == total SWAR degree
#pragma unroll
            for (int j = 0; j < 4; ++j) {
                int dg = (run >> (8 * j)) & 0xff;
                deg[4 * c4 + j] = dg;
                dinv[4 * c4 + j] = rsqrtf((float)(dg + 1));   // +1 self loop
            }
        }
    }
}

// ---------------- fp8 helpers (OCP e4m3 on gfx950) ----------------
__device__ __forceinline__ unsigned char f8enc(float v) {
    return (unsigned char)(__builtin_amdgcn_cvt_pk_fp8_f32(v, v, 0, false) & 0xff);
}
// 16B row chunk: 8 cvt_pk + 8 v_pk_add_f32
__device__ __forceinline__ void add16f8(f32x2* a, uint4 u) {
    a[0] += __builtin_amdgcn_cvt_pk_f32_fp8(u.x, false);
    a[1] += __builtin_amdgcn_cvt_pk_f32_fp8(u.x, true);
    a[2] += __builtin_amdgcn_cvt_pk_f32_fp8(u.y, false);
    a[3] += __builtin_amdgcn_cvt_pk_f32_fp8(u.y, true);
    a[4] += __builtin_amdgcn_cvt_pk_f32_fp8(u.z, false);
    a[5] += __builtin_amdgcn_cvt_pk_f32_fp8(u.z, true);
    a[6] += __builtin_amdgcn_cvt_pk_f32_fp8(u.w, false);
    a[7] += __builtin_amdgcn_cvt_pk_f32_fp8(u.w, true);
}

// ---------------- MFMA GEMM: out8[r] = fp8(dinv[r] * (A[r] @ W)) -----------
__device__ __forceinline__ half8 ldA(const float* rowp, int koff) {
    float4 u0 = *(const float4*)(rowp + koff);
    float4 u1 = *(const float4*)(rowp + koff + 4);
    half8 r;
    r[0] = (_Float16)u0.x; r[1] = (_Float16)u0.y;
    r[2] = (_Float16)u0.z; r[3] = (_Float16)u0.w;
    r[4] = (_Float16)u1.x; r[5] = (_Float16)u1.y;
    r[6] = (_Float16)u1.z; r[7] = (_Float16)u1.w;
    return r;
}
// fp8 A rows: decode 8 bytes -> 8 halves (fp8 subset of fp16: exact)
__device__ __forceinline__ half8 ldA(const unsigned char* rowp, int koff) {
    uint2 u = *(const uint2*)(rowp + koff);
    f32x2 f0 = __builtin_amdgcn_cvt_pk_f32_fp8(u.x, false);
    f32x2 f1 = __builtin_amdgcn_cvt_pk_f32_fp8(u.x, true);
    f32x2 f2 = __builtin_amdgcn_cvt_pk_f32_fp8(u.y, false);
    f32x2 f3 = __builtin_amdgcn_cvt_pk_f32_fp8(u.y, true);
    half8 r;
    r[0] = (_Float16)f0[0]; r[1] = (_Float16)f0[1];
    r[2] = (_Float16)f1[0]; r[3] = (_Float16)f1[1];
    r[4] = (_Float16)f2[0]; r[5] = (_Float16)f2[1];
    r[6] = (_Float16)f3[0]; r[7] = (_Float16)f3[1];
    return r;
}

template <typename TA>
__device__ __forceinline__ void mfma_gemm(const TA* __restrict__ A,
                                          const __half* __restrict__ Wt,
                                          const float* __restrict__ dinv,
                                          unsigned char* __restrict__ out8,
                                          int row0, int tid) {
    int wave = tid >> 6, lane = tid & 63;
    int quad = lane >> 4, c16 = lane & 15;
    int m0 = row0 + wave * 32;
    int ra = m0 + c16;      if (ra >= N) ra = 0;   // OOB rows: dummy read row 0
    int rb = m0 + 16 + c16; if (rb >= N) rb = 0;
    const TA* pa = A + (size_t)ra * D;
    const TA* pb = A + (size_t)rb * D;

    f32x4 acc[2][8];
#pragma unroll
    for (int i = 0; i < 2; ++i)
#pragma unroll
        for (int j = 0; j < 8; ++j) acc[i][j] = (f32x4){0.f, 0.f, 0.f, 0.f};

#pragma unroll
    for (int kq = 0; kq < 4; ++kq) {
        int koff = kq * 32 + quad * 8;
        half8 a0 = ldA(pa, koff);
        half8 a1 = ldA(pb, koff);
#pragma unroll
        for (int nt = 0; nt < 8; ++nt) {
            half8 bf = *(const half8*)(Wt + (size_t)(nt * 16 + c16) * D + koff);
            acc[0][nt] = __builtin_amdgcn_mfma_f32_16x16x32_f16(a0, bf, acc[0][nt], 0, 0, 0);
            acc[1][nt] = __builtin_amdgcn_mfma_f32_16x16x32_f16(a1, bf, acc[1][nt], 0, 0, 0);
        }
    }

    // C/D: col = lane&15, row = quad*4 + reg
#pragma unroll
    for (int rt = 0; rt < 2; ++rt) {
        int mt = m0 + rt * 16;
#pragma unroll
        for (int i = 0; i < 4; ++i) {
            int grow = mt + quad * 4 + i;
            if (grow < N) {
                float s = dinv[grow];
                unsigned char* orow = out8 + (size_t)grow * D + c16;
#pragma unroll
                for (int nt = 0; nt < 8; ++nt)
                    orow[nt * 16] = f8enc(acc[rt][nt][i] * s);
            }
        }
    }
}

// ---------------- Phase C fused: parallel rank-scatter + GEMM-1 -------------
__global__ __launch_bounds__(256) void k_fuse(const int* __restrict__ ei,
                                              const unsigned char* __restrict__ hist,
                                              const unsigned char* __restrict__ rank,
                                              unsigned short* __restrict__ csr,
                                              const float* __restrict__ x,
                                              const __half* __restrict__ Wt1,
                                              const float* __restrict__ dinv,
                                              unsigned char* __restrict__ out8) {
    int b = blockIdx.x, m = b % 3;
    if (m < 2) {
        // ---- scatter: 4 consecutive edges/thread, vector loads ----
        int sb = (b / 3) * 2 + m;                 // 0..781
        int e0 = sb * 1024 + threadIdx.x * 4;
        if (e0 >= E) return;
        int4 rr = *(const int4*)(ei + e0);
        int4 cc = *(const int4*)(ei + E + e0);
        uchar4 kk = *(const uchar4*)(rank + e0);
        int rs[4] = {rr.x, rr.y, rr.z, rr.w};
        int cs[4] = {cc.x, cc.y, cc.z, cc.w};
        int ks[4] = {kk.x, kk.y, kk.z, kk.w};
#pragma unroll
        for (int i = 0; i < 4; ++i) {
            int e = e0 + i;
            int c = cs[i];
            int chunk = e / EPB;
            int slot = (int)hist[(size_t)chunk * 50000 + c] + ks[i];
            if (slot < CAP) csr[(c << 6) + slot] = (unsigned short)rs[i];
        }
        return;
    }
    // ---- gemm branch ----
    mfma_gemm<float>(x, Wt1, dinv, out8, (b / 3) * 128, threadIdx.x);
}

// ---------------- Aggregation core v2: wide-issue gather -------------------
// 8 edge slots x 8 lanes x uint4(16B): one VMEM instr covers 8 full rows.
// Issue-then-consume full unroll (8 csr loads, then 8 masked row gathers,
// then decodes): up to 64 rows in flight per wave. Reduce over lane bits
// 3/4/5 (shfl_xor 8/16/32). a0out[16] = channels (lane&7)*16 .. +15, valid
// on lanes 0..7.
__device__ __forceinline__ float agg_core(int c, int lane,
                                          const unsigned char* __restrict__ hs8,
                                          const int* __restrict__ deg,
                                          const unsigned short* __restrict__ csr,
                                          float* __restrict__ a0out) {
    int qw = lane >> 3;         // 0..7: edge slot
    int q  = lane & 7;          // 16B group within row
    int dgRaw = deg[c];
    int dg = dgRaw < CAP ? dgRaw : CAP;
    float dc = rsqrtf((float)(dgRaw + 1));
    int e0 = c << 6;
    int boff = q * 16;

    // csr indices upfront (unmasked; addresses always in-bounds, garbage
    // values only used under the dg mask below)
    int r[8];
#pragma unroll
    for (int b = 0; b < 8; ++b) r[b] = csr[e0 + b * 8 + qw];

    uint4 us;
    bool selfv = (qw == 0);     // self loop (hs8[c] already = dinv[c]*h[c])
    if (selfv) us = *(const uint4*)&hs8[((unsigned)c << 7) + boff];

    // all row gathers issued before any consumption
    uint4 u[8];
#pragma unroll
    for (int b = 0; b < 8; ++b)
        if (b * 8 + qw < dg)
            u[b] = *(const uint4*)&hs8[((unsigned)r[b] << 7) + boff];

    f32x2 acc[8];
#pragma unroll
    for (int i = 0; i < 8; ++i) acc[i] = (f32x2){0.f, 0.f};
    if (selfv) add16f8(acc, us);
#pragma unroll
    for (int b = 0; b < 8; ++b)
        if (b * 8 + qw < dg) add16f8(acc, u[b]);

#pragma unroll
    for (int t = 0; t < 16; ++t) {
        float v = acc[t >> 1][t & 1];
        v += __shfl_xor(v, 8, 64);
        v += __shfl_xor(v, 16, 64);
        v += __shfl_xor(v, 32, 64);
        a0out[t] = v;
    }
    return dc;
}

// layer-1 agg: writes fp8 h1 rows (gemm2 decodes fp8->fp16)
__global__ __launch_bounds__(256) void k_agg1(const unsigned char* __restrict__ hs8,
                                              const int* __restrict__ deg,
                                              const unsigned short* __restrict__ csr,
                                              const float* __restrict__ bias,
                                              unsigned char* __restrict__ out8) {
    int wave = threadIdx.x >> 6;
    int lane = threadIdx.x & 63;
    int c = blockIdx.x * 4 + wave;
    float a0[16];
    float dc = agg_core(c, lane, hs8, deg, csr, a0);
    if (lane < 8) {
        int q = lane;
        union { unsigned char b[16]; uint4 u; } p;
#pragma unroll
        for (int i = 0; i < 16; ++i)
            p.b[i] = f8enc(fmaxf(fmaf(dc, a0[i], bias[q * 16 + i]), 0.f));
        *(uint4*)&out8[((unsigned)c << 7) + q * 16] = p.u;
    }
}

// ---------------- GEMM layer 2 (fp8 A -> fp8 out) ----------------
__global__ __launch_bounds__(256) void k_gemm(const unsigned char* __restrict__ A,
                                              const __half* __restrict__ Wt,
                                              const float* __restrict__ dinv,
                                              unsigned char* __restrict__ out8) {
    mfma_gemm<unsigned char>(A, Wt, dinv, out8, blockIdx.x * 128, threadIdx.x);
}

// layer-2 agg: reduces h2 rows straight into per-block pool partials
__global__ __launch_bounds__(256) void k_agg2(const unsigned char* __restrict__ hs8,
                                              const int* __restrict__ deg,
                                              const unsigned short* __restrict__ csr,
                                              const float* __restrict__ bias,
                                              float* __restrict__ gpart) {
    __shared__ float gblk[4][128];
    int wave = threadIdx.x >> 6;
    int lane = threadIdx.x & 63;
    int c = blockIdx.x * 4 + wave;
    float a0[16];
    float dc = agg_core(c, lane, hs8, deg, csr, a0);
    if (lane < 8) {
        int q = lane;
#pragma unroll
        for (int i = 0; i < 16; ++i)
            gblk[wave][q * 16 + i] = fmaxf(fmaf(dc, a0[i], bias[q * 16 + i]), 0.f);
    }
    __syncthreads();
    int t = threadIdx.x;
    if (t < 128)
        gpart[(size_t)blockIdx.x * 128 + t] =
            gblk[0][t] + gblk[1][t] + gblk[2][t] + gblk[3][t];
}

// ---------------- Pool stage 2: 12500 partials -> 256 partials --------------
__global__ __launch_bounds__(256) void k_pool(const float* __restrict__ gpart,
                                              float* __restrict__ gpart2) {
    int d = threadIdx.x & 127;
    int half = threadIdx.x >> 7;
    int b = blockIdx.x;                 // 256 blocks
    int per = (NW + 255) / 256;         // 49
    int r0 = b * per;
    int r1 = r0 + per;
    if (r1 > NW) r1 = NW;
    float acc = 0.f;
    for (int r = r0 + half; r < r1; r += 2)
        acc += gpart[(size_t)r * D + d];
    __shared__ float red[256];
    red[threadIdx.x] = acc;
    __syncthreads();
    if (half == 0) gpart2[(size_t)b * D + d] = red[d] + red[128 + d];
}

// ---------------- Final: g = sum(gpart2)/N; out = g@Wc + bc ----------------
__global__ __launch_bounds__(512) void k_final(const float* __restrict__ gpart2,
                                               const float* __restrict__ Wc,
                                               const float* __restrict__ bc,
                                               float* __restrict__ out) {
    __shared__ float g[D];
    __shared__ float red[512];
    int t = threadIdx.x;
    int d = t & 127, grp = t >> 7;
    float s = 0.f;
#pragma unroll 4
    for (int w = grp * 64; w < grp * 64 + 64; ++w)
        s += gpart2[(size_t)w * D + d];
    red[t] = s;
    __syncthreads();
    if (grp == 0)
        g[d] = (red[d] + red[128 + d] + red[256 + d] + red[384 + d]) * (1.0f / (float)N);
    __syncthreads();
    if (t < DOUT) {
        float acc = bc[t];
        for (int dd = 0; dd < D; ++dd) acc = fmaf(g[dd], Wc[dd * DOUT + t], acc);
        out[t] = acc;
    }
}

extern "C" void kernel_launch(void* const* d_in, const int* in_sizes, int n_in,
                              void* d_out, int out_size, void* d_ws, size_t ws_size,
                              hipStream_t stream) {
    const float* x  = (const float*)d_in[0];
    const int*   ei = (const int*)d_in[1];
    const float* W1 = (const float*)d_in[2];
    const float* b1 = (const float*)d_in[3];
    const float* W2 = (const float*)d_in[4];
    const float* b2 = (const float*)d_in[5];
    const float* Wc = (const float*)d_in[6];
    const float* bc = (const float*)d_in[7];
    float* out = (float*)d_out;

    char* ws = (char*)d_ws;
    size_t off = 0;
    auto alloc = [&](size_t bytes) {
        void* p = ws + off;
        off += (bytes + 511) & ~(size_t)511;
        return p;
    };
    unsigned char*  hist   = (unsigned char*) alloc((size_t)HB * 50000);     // 3.2MB
    unsigned char*  rank   = (unsigned char*) alloc((size_t)E);              // 0.8MB
    int*            deg    = (int*)           alloc((size_t)N * 4);
    float*          dinv   = (float*)         alloc((size_t)N * 4);
    unsigned short* csr    = (unsigned short*)alloc((size_t)N * CAP * 2);    // 6.4MB
    unsigned char*  hs8    = (unsigned char*) alloc((size_t)N * D);          // 6.4MB
    unsigned char*  h18    = (unsigned char*) alloc((size_t)N * D);          // 6.4MB (fp8 h1 act)
    __half*         Wt1    = (__half*)        alloc((size_t)D * D * 2);      // 32KB
    __half*         Wt2    = (__half*)        alloc((size_t)D * D * 2);      // 32KB
    float*          gpart  = (float*)         alloc((size_t)NW * D * 4);     // 6.4MB
    float*          gpart2 = (float*)         alloc((size_t)256 * D * 4);
    (void)ws_size; (void)in_sizes; (void)n_in; (void)out_size;

    const int* col = ei + E;

    // Phase A: histograms + ranks + W transposes (one dispatch)
    k_hist<<<HB + 32, 1024, 0, stream>>>(col, hist, rank, W1, W2, Wt1, Wt2);
    // Phase B: per-node prefix (register-staged 4-quarter scan); deg/dinv
    k_colscan<<<(HWRD + 63) / 64, 256, 0, stream>>>(hist, deg, dinv);
    // Phase C: parallel scatter (2/3) + MFMA gemm layer 1 (1/3) -> fp8 rows
    k_fuse<<<GF, 256, 0, stream>>>(ei, hist, rank, csr, x, Wt1, dinv, hs8);

    k_agg1<<<NW, 256, 0, stream>>>(hs8, deg, csr, b1, h18);
    k_gemm<<<GM, 256, 0, stream>>>(h18, Wt2, dinv, hs8);
    k_agg2<<<NW, 256, 0, stream>>>(hs8, deg, csr, b2, gpart);
    k_pool<<<256, 256, 0, stream>>>(gpart, gpart2);
    k_final<<<1, 512, 0, stream>>>(gpart2, Wc, bc, out);
}

// Round 7
// 209.375 us; speedup vs baseline: 1.0192x; 1.0192x over previous
//
#include <hip/hip_runtime.h>
#include <hip/hip_fp16.h>

// GCN: h1 = relu(Agg(x@W1)+b1); h2 = relu(Agg(h1@W2)+b2); out = mean(h2)@Wc+bc
// norm(r,c)=dinv[r]*dinv[c].
// R1-R13: see history. Best structure: zero-atomic CSR + MFMA gemms + fp8 rows.
// R14/R15: agg+gemm fusion dead. R16: pk_add (208.6). R17: two-pass dead.
// R18: fp8 hact + reg-staged colscan (206.96, best). R19: wide-issue gather +
//      HB64 = 213.4 REGRESSION (exec-mask branches broke load clustering;
//      HB64 halved k_hist parallelism). FOURTH failed agg theory => aggs are
//      at a scattered-miss service floor (~33us per pass over 6.4MB ws,
//      FETCH ~33MB, no pipe saturated). Stop touching the gather core.
// R20: (this round) revert to R18 exactly; exploit GEMM linearity to swap
//      layer-2 gemm and agg:  Sum norm*(h1@W2) == (Sum norm*h1)@W2.
//      agg1 -> s1 = fp8(dinv_c*relu(h1));  agg2p = PURE gather-sum -> A fp8;
//      gemmpool = relu(A@W2+b2) + in-block column reduce -> 391 pool partials.
//      Kills k_pool (8->7 launches) + ~13MB streaming. Agg core untouched.

typedef _Float16 half8 __attribute__((ext_vector_type(8)));
typedef float f32x4 __attribute__((ext_vector_type(4)));
typedef float f32x2 __attribute__((ext_vector_type(2)));

constexpr int N = 50000;
constexpr int E = 800000;
constexpr int D = 128;
constexpr int DOUT = 40;
constexpr int CAP = 64;               // slots/node (Poisson(16) tail ~1e-18)
constexpr int HB = 128;               // histogram chunks
constexpr int EPB = E / HB;           // 6250 edges/chunk
constexpr int HWRD = 12500;           // 50000 bytes = 12500 words
constexpr int GM = (N + 127) / 128;   // 391 gemm blocks
constexpr int NW = N / 4;             // 12500 agg blocks
constexpr int GF = 3 * GM;            // 1173 = 782 scatter + 391 gemm

// ---------------- Phase A: chunk histograms + per-edge rank + W transpose ---
__global__ __launch_bounds__(1024) void k_hist(const int* __restrict__ col,
                                               unsigned char* __restrict__ hist,
                                               unsigned char* __restrict__ rank,
                                               const float* __restrict__ W1,
                                               const float* __restrict__ W2,
                                               __half* __restrict__ T1,
                                               __half* __restrict__ T2) {
    __shared__ unsigned int h[HWRD];
    int b = blockIdx.x, t = threadIdx.x;
    if (b >= HB) {                        // 32 spare blocks: Wt[n][k]=fp16(W[k][n])
        int o = (b - HB) * 1024 + t;      // 0..32767
        const float* W = (o < 16384) ? W1 : W2;
        __half* T = (o < 16384) ? T1 : T2;
        int oo = o & 16383;
        int n = oo >> 7, k = oo & 127;
        T[oo] = (__half)W[k * 128 + n];
        return;
    }
    for (int i = t; i < HWRD; i += 1024) h[i] = 0;
    __syncthreads();
    int e0 = b * EPB;
    for (int e = e0 + t; e < e0 + EPB; e += 1024) {
        int c = col[e];
        unsigned int old = atomicAdd(&h[c >> 2], 1u << ((c & 3) * 8));
        rank[e] = (unsigned char)((old >> ((c & 3) * 8)) & 0xff);
    }
    __syncthreads();
    unsigned int* out = (unsigned int*)(hist + (size_t)b * 50000);
    for (int i = t; i < HWRD; i += 1024) out[i] = h[i];
}

// ---------------- Phase B: per-node prefix over chunks; deg + dinv ---------
// SWAR dwords (4 nodes/word, deg<=255 so no cross-byte carry). 4 threads per
// column, each scans 32 chunks into registers; LDS-combine quarter sums.
__global__ __launch_bounds__(256) void k_colscan(unsigned char* __restrict__ hist,
                                                 int* __restrict__ deg,
                                                 float* __restrict__ dinv) {
    __shared__ unsigned int part[4][64];
    unsigned int* hw = (unsigned int*)hist;
    int c4 = blockIdx.x * 64 + (threadIdx.x & 63);
    int qq = threadIdx.x >> 6;            // chunk quarter 0..3
    bool ok = c4 < HWRD;
    unsigned int v[32];
    unsigned int s = 0;
    if (ok) {
#pragma unroll
        for (int i = 0; i < 32; ++i) v[i] = hw[(size_t)(qq * 32 + i) * HWRD + c4];
#pragma unroll
        for (int i = 0; i < 32; ++i) s += v[i];
    }
    part[qq][threadIdx.x & 63] = s;
    __syncthreads();
    unsigned int base = 0;
    for (int k = 0; k < qq; ++k) base += part[k][threadIdx.x & 63];
    if (ok) {
        unsigned int run = base;
#pragma unroll
        for (int i = 0; i < 32; ++i) {
            hw[(size_t)(qq * 32 + i) * HWRD + c4] = run;   // exclusive prefix
            run += v[i];
        }
        if (qq == 3) {                    // run == total SWAR degree
#pragma unroll
            for (int j = 0; j < 4; ++j) {
                int dg = (run >> (8 * j)) & 0xff;
                deg[4 * c4 + j] = dg;
                dinv[4 * c4 + j] = rsqrtf((float)(dg + 1));   // +1 self loop
            }
        }
    }
}

// ---------------- fp8 helpers (OCP e4m3 on gfx950) ----------------
__device__ __forceinline__ unsigned char f8enc(float v) {
    return (unsigned char)(__builtin_amdgcn_cvt_pk_fp8_f32(v, v, 0, false) & 0xff);
}
// packed: 4 cvt + 4 v_pk_add_f32 per 8 bytes
__device__ __forceinline__ void add8f8(f32x2* a, uint2 u) {
    a[0] += __builtin_amdgcn_cvt_pk_f32_fp8(u.x, false);
    a[1] += __builtin_amdgcn_cvt_pk_f32_fp8(u.x, true);
    a[2] += __builtin_amdgcn_cvt_pk_f32_fp8(u.y, false);
    a[3] += __builtin_amdgcn_cvt_pk_f32_fp8(u.y, true);
}

// ---------------- A-operand loaders ----------------
__device__ __forceinline__ half8 ldA(const float* rowp, int koff) {
    float4 u0 = *(const float4*)(rowp + koff);
    float4 u1 = *(const float4*)(rowp + koff + 4);
    half8 r;
    r[0] = (_Float16)u0.x; r[1] = (_Float16)u0.y;
    r[2] = (_Float16)u0.z; r[3] = (_Float16)u0.w;
    r[4] = (_Float16)u1.x; r[5] = (_Float16)u1.y;
    r[6] = (_Float16)u1.z; r[7] = (_Float16)u1.w;
    return r;
}
// fp8 A rows: decode 8 bytes -> 8 halves (fp8 subset of fp16: exact)
__device__ __forceinline__ half8 ldA(const unsigned char* rowp, int koff) {
    uint2 u = *(const uint2*)(rowp + koff);
    f32x2 f0 = __builtin_amdgcn_cvt_pk_f32_fp8(u.x, false);
    f32x2 f1 = __builtin_amdgcn_cvt_pk_f32_fp8(u.x, true);
    f32x2 f2 = __builtin_amdgcn_cvt_pk_f32_fp8(u.y, false);
    f32x2 f3 = __builtin_amdgcn_cvt_pk_f32_fp8(u.y, true);
    half8 r;
    r[0] = (_Float16)f0[0]; r[1] = (_Float16)f0[1];
    r[2] = (_Float16)f1[0]; r[3] = (_Float16)f1[1];
    r[4] = (_Float16)f2[0]; r[5] = (_Float16)f2[1];
    r[6] = (_Float16)f3[0]; r[7] = (_Float16)f3[1];
    return r;
}

// ---------------- MFMA GEMM 1: out8[r] = fp8(dinv[r] * (x[r] @ W1)) --------
__device__ __forceinline__ void mfma_gemm1(const float* __restrict__ A,
                                           const __half* __restrict__ Wt,
                                           const float* __restrict__ dinv,
                                           unsigned char* __restrict__ out8,
                                           int row0, int tid) {
    int wave = tid >> 6, lane = tid & 63;
    int quad = lane >> 4, c16 = lane & 15;
    int m0 = row0 + wave * 32;
    int ra = m0 + c16;      if (ra >= N) ra = 0;   // OOB rows: dummy read row 0
    int rb = m0 + 16 + c16; if (rb >= N) rb = 0;
    const float* pa = A + (size_t)ra * D;
    const float* pb = A + (size_t)rb * D;

    f32x4 acc[2][8];
#pragma unroll
    for (int i = 0; i < 2; ++i)
#pragma unroll
        for (int j = 0; j < 8; ++j) acc[i][j] = (f32x4){0.f, 0.f, 0.f, 0.f};

#pragma unroll
    for (int kq = 0; kq < 4; ++kq) {
        int koff = kq * 32 + quad * 8;
        half8 a0 = ldA(pa, koff);
        half8 a1 = ldA(pb, koff);
#pragma unroll
        for (int nt = 0; nt < 8; ++nt) {
            half8 bf = *(const half8*)(Wt + (size_t)(nt * 16 + c16) * D + koff);
            acc[0][nt] = __builtin_amdgcn_mfma_f32_16x16x32_f16(a0, bf, acc[0][nt], 0, 0, 0);
            acc[1][nt] = __builtin_amdgcn_mfma_f32_16x16x32_f16(a1, bf, acc[1][nt], 0, 0, 0);
        }
    }

    // C/D: col = lane&15, row = quad*4 + reg
#pragma unroll
    for (int rt = 0; rt < 2; ++rt) {
        int mt = m0 + rt * 16;
#pragma unroll
        for (int i = 0; i < 4; ++i) {
            int grow = mt + quad * 4 + i;
            if (grow < N) {
                float s = dinv[grow];
                unsigned char* orow = out8 + (size_t)grow * D + c16;
#pragma unroll
                for (int nt = 0; nt < 8; ++nt)
                    orow[nt * 16] = f8enc(acc[rt][nt][i] * s);
            }
        }
    }
}

// ---------------- Phase C fused: parallel rank-scatter + GEMM-1 -------------
__global__ __launch_bounds__(256) void k_fuse(const int* __restrict__ ei,
                                              const unsigned char* __restrict__ hist,
                                              const unsigned char* __restrict__ rank,
                                              unsigned short* __restrict__ csr,
                                              const float* __restrict__ x,
                                              const __half* __restrict__ Wt1,
                                              const float* __restrict__ dinv,
                                              unsigned char* __restrict__ out8) {
    int b = blockIdx.x, m = b % 3;
    if (m < 2) {
        // ---- scatter: 4 consecutive edges/thread, vector loads ----
        int sb = (b / 3) * 2 + m;                 // 0..781
        int e0 = sb * 1024 + threadIdx.x * 4;
        if (e0 >= E) return;
        int4 rr = *(const int4*)(ei + e0);
        int4 cc = *(const int4*)(ei + E + e0);
        uchar4 kk = *(const uchar4*)(rank + e0);
        int rs[4] = {rr.x, rr.y, rr.z, rr.w};
        int cs[4] = {cc.x, cc.y, cc.z, cc.w};
        int ks[4] = {kk.x, kk.y, kk.z, kk.w};
#pragma unroll
        for (int i = 0; i < 4; ++i) {
            int e = e0 + i;
            int c = cs[i];
            int chunk = e / EPB;
            int slot = (int)hist[(size_t)chunk * 50000 + c] + ks[i];
            if (slot < CAP) csr[(c << 6) + slot] = (unsigned short)rs[i];
        }
        return;
    }
    // ---- gemm branch ----
    mfma_gemm1(x, Wt1, dinv, out8, (b / 3) * 128, threadIdx.x);
}

// ---------------- Aggregation core (1 wave/node, fp8 row-sum, pk_add) ------
// EXACT R16/R18 shape: 4 edges x 16 lanes x 8B, 4 acc sets, shfl 16/32.
__device__ __forceinline__ float agg_core(int c, int lane,
                                          const unsigned char* __restrict__ hs8,
                                          const int* __restrict__ deg,
                                          const unsigned short* __restrict__ csr,
                                          float* __restrict__ a0out) {
    int qw = lane >> 4;         // 0..3: edge within group of 4
    int q  = lane & 15;         // column group: bytes q*8..q*8+7
    int dgRaw = deg[c];
    int dg = dgRaw < CAP ? dgRaw : CAP;
    float dc = rsqrtf((float)(dgRaw + 1));
    int e0 = c << 6;

    f32x2 a0[4], a1[4], a2[4], a3[4];
#pragma unroll
    for (int i = 0; i < 4; ++i) {
        a0[i] = (f32x2){0.f, 0.f}; a1[i] = (f32x2){0.f, 0.f};
        a2[i] = (f32x2){0.f, 0.f}; a3[i] = (f32x2){0.f, 0.f};
    }
    if (qw == 0)                // self loop (row c already dinv-prescaled)
        add8f8(a0, *(const uint2*)&hs8[((unsigned)c << 7) + q * 8]);

    int j = 0;
    for (; j + 16 <= dg; j += 16) {
        int r0 = csr[e0 + j + qw];
        int r1 = csr[e0 + j + 4 + qw];
        int r2 = csr[e0 + j + 8 + qw];
        int r3 = csr[e0 + j + 12 + qw];
        uint2 u0 = *(const uint2*)&hs8[((unsigned)r0 << 7) + q * 8];
        uint2 u1 = *(const uint2*)&hs8[((unsigned)r1 << 7) + q * 8];
        uint2 u2 = *(const uint2*)&hs8[((unsigned)r2 << 7) + q * 8];
        uint2 u3 = *(const uint2*)&hs8[((unsigned)r3 << 7) + q * 8];
        add8f8(a0, u0); add8f8(a1, u1); add8f8(a2, u2); add8f8(a3, u3);
    }
    if (j + 8 <= dg) {
        int r0 = csr[e0 + j + qw];
        int r1 = csr[e0 + j + 4 + qw];
        uint2 u0 = *(const uint2*)&hs8[((unsigned)r0 << 7) + q * 8];
        uint2 u1 = *(const uint2*)&hs8[((unsigned)r1 << 7) + q * 8];
        add8f8(a0, u0); add8f8(a1, u1);
        j += 8;
    }
    if (j + 4 <= dg) {
        int r0 = csr[e0 + j + qw];
        add8f8(a0, *(const uint2*)&hs8[((unsigned)r0 << 7) + q * 8]);
        j += 4;
    }
    int rem = dg - j;                     // 0..3
    if (qw < rem) {
        int r0 = csr[e0 + j + qw];
        add8f8(a1, *(const uint2*)&hs8[((unsigned)r0 << 7) + q * 8]);
    }

#pragma unroll
    for (int i = 0; i < 4; ++i) { a0[i] += a1[i]; a2[i] += a3[i]; a0[i] += a2[i]; }
#pragma unroll
    for (int t = 0; t < 8; ++t) {
        float v = a0[t >> 1][t & 1];
        v += __shfl_xor(v, 16, 64);
        v += __shfl_xor(v, 32, 64);
        a0out[t] = v;
    }
    return dc;
}

// layer-1 agg: s1[c] = fp8( dinv[c] * relu(dc*Sum + b1) )
__global__ __launch_bounds__(256) void k_agg1(const unsigned char* __restrict__ hs8,
                                              const int* __restrict__ deg,
                                              const unsigned short* __restrict__ csr,
                                              const float* __restrict__ bias,
                                              const float* __restrict__ dinv,
                                              unsigned char* __restrict__ out8) {
    int wave = threadIdx.x >> 6;
    int lane = threadIdx.x & 63;
    int c = blockIdx.x * 4 + wave;
    float a0[8];
    float dc = agg_core(c, lane, hs8, deg, csr, a0);
    if ((lane >> 4) == 0) {
        int q = lane & 15;
        float sc = dinv[c];
        union { unsigned char b[8]; uint2 u; } p;
#pragma unroll
        for (int i = 0; i < 8; ++i)
            p.b[i] = f8enc(sc * fmaxf(fmaf(dc, a0[i], bias[q * 8 + i]), 0.f));
        *(uint2*)&out8[((unsigned)c << 7) + q * 8] = p.u;
    }
}

// layer-2 agg (pure, pre-gemm): A[c] = fp8( dc * (Sum s1 + self) )
__global__ __launch_bounds__(256) void k_agg2p(const unsigned char* __restrict__ s1,
                                               const int* __restrict__ deg,
                                               const unsigned short* __restrict__ csr,
                                               unsigned char* __restrict__ outA) {
    int wave = threadIdx.x >> 6;
    int lane = threadIdx.x & 63;
    int c = blockIdx.x * 4 + wave;
    float a0[8];
    float dc = agg_core(c, lane, s1, deg, csr, a0);
    if ((lane >> 4) == 0) {
        int q = lane & 15;
        union { unsigned char b[8]; uint2 u; } p;
#pragma unroll
        for (int i = 0; i < 8; ++i)
            p.b[i] = f8enc(dc * a0[i]);
        *(uint2*)&outA[((unsigned)c << 7) + q * 8] = p.u;
    }
}

// ---------------- GEMM-2 + fused pool: gpart[b] = Sum_rows relu(A@W2+b2) ----
__global__ __launch_bounds__(256) void k_gemmpool(const unsigned char* __restrict__ A,
                                                  const __half* __restrict__ Wt,
                                                  const float* __restrict__ bias,
                                                  float* __restrict__ gpart) {
    __shared__ float colsum[4][128];
    int tid = threadIdx.x;
    int wave = tid >> 6, lane = tid & 63;
    int quad = lane >> 4, c16 = lane & 15;
    int m0 = blockIdx.x * 128 + wave * 32;
    int ra = m0 + c16;      if (ra >= N) ra = 0;
    int rb = m0 + 16 + c16; if (rb >= N) rb = 0;
    const unsigned char* pa = A + (size_t)ra * D;
    const unsigned char* pb = A + (size_t)rb * D;

    f32x4 acc[2][8];
#pragma unroll
    for (int i = 0; i < 2; ++i)
#pragma unroll
        for (int j = 0; j < 8; ++j) acc[i][j] = (f32x4){0.f, 0.f, 0.f, 0.f};

#pragma unroll
    for (int kq = 0; kq < 4; ++kq) {
        int koff = kq * 32 + quad * 8;
        half8 a0 = ldA(pa, koff);
        half8 a1 = ldA(pb, koff);
#pragma unroll
        for (int nt = 0; nt < 8; ++nt) {
            half8 bf = *(const half8*)(Wt + (size_t)(nt * 16 + c16) * D + koff);
            acc[0][nt] = __builtin_amdgcn_mfma_f32_16x16x32_f16(a0, bf, acc[0][nt], 0, 0, 0);
            acc[1][nt] = __builtin_amdgcn_mfma_f32_16x16x32_f16(a1, bf, acc[1][nt], 0, 0, 0);
        }
    }

    // column partial sums of relu(acc + b2): rows masked to < N.
    // lane covers rows quad*4+i (rt in {0,1}); reduce over quads via shfl.
#pragma unroll
    for (int nt = 0; nt < 8; ++nt) {
        float bv = bias[nt * 16 + c16];
        float s = 0.f;
#pragma unroll
        for (int rt = 0; rt < 2; ++rt) {
#pragma unroll
            for (int i = 0; i < 4; ++i) {
                int grow = m0 + rt * 16 + quad * 4 + i;
                if (grow < N) s += fmaxf(acc[rt][nt][i] + bv, 0.f);
            }
        }
        s += __shfl_xor(s, 16, 64);
        s += __shfl_xor(s, 32, 64);
        if (quad == 0) colsum[wave][nt * 16 + c16] = s;
    }
    __syncthreads();
    if (tid < 128)
        gpart[(size_t)blockIdx.x * 128 + tid] =
            colsum[0][tid] + colsum[1][tid] + colsum[2][tid] + colsum[3][tid];
}

// ---------------- Final: g = sum(gpart)/N; out = g@Wc + bc ----------------
__global__ __launch_bounds__(512) void k_final(const float* __restrict__ gpart,
                                               const float* __restrict__ Wc,
                                               const float* __restrict__ bc,
                                               float* __restrict__ out) {
    __shared__ float g[D];
    __shared__ float red[512];
    int t = threadIdx.x;
    int d = t & 127, grp = t >> 7;
    float s = 0.f;
    for (int w = grp; w < GM; w += 4)
        s += gpart[(size_t)w * D + d];
    red[t] = s;
    __syncthreads();
    if (grp == 0)
        g[d] = (red[d] + red[128 + d] + red[256 + d] + red[384 + d]) * (1.0f / (float)N);
    __syncthreads();
    if (t < DOUT) {
        float acc = bc[t];
        for (int dd = 0; dd < D; ++dd) acc = fmaf(g[dd], Wc[dd * DOUT + t], acc);
        out[t] = acc;
    }
}

extern "C" void kernel_launch(void* const* d_in, const int* in_sizes, int n_in,
                              void* d_out, int out_size, void* d_ws, size_t ws_size,
                              hipStream_t stream) {
    const float* x  = (const float*)d_in[0];
    const int*   ei = (const int*)d_in[1];
    const float* W1 = (const float*)d_in[2];
    const float* b1 = (const float*)d_in[3];
    const float* W2 = (const float*)d_in[4];
    const float* b2 = (const float*)d_in[5];
    const float* Wc = (const float*)d_in[6];
    const float* bc = (const float*)d_in[7];
    float* out = (float*)d_out;

    char* ws = (char*)d_ws;
    size_t off = 0;
    auto alloc = [&](size_t bytes) {
        void* p = ws + off;
        off += (bytes + 511) & ~(size_t)511;
        return p;
    };
    unsigned char*  hist   = (unsigned char*) alloc((size_t)HB * 50000);     // 6.4MB
    unsigned char*  rank   = (unsigned char*) alloc((size_t)E);              // 0.8MB
    int*            deg    = (int*)           alloc((size_t)N * 4);
    float*          dinv   = (float*)         alloc((size_t)N * 4);
    unsigned short* csr    = (unsigned short*)alloc((size_t)N * CAP * 2);    // 6.4MB
    unsigned char*  hs8    = (unsigned char*) alloc((size_t)N * D);          // 6.4MB (gemm1 rows)
    unsigned char*  s18    = (unsigned char*) alloc((size_t)N * D);          // 6.4MB (s1 = dinv*h1)
    unsigned char*  aact   = (unsigned char*) alloc((size_t)N * D);          // 6.4MB (A = dc*Sum s1)
    __half*         Wt1    = (__half*)        alloc((size_t)D * D * 2);      // 32KB
    __half*         Wt2    = (__half*)        alloc((size_t)D * D * 2);      // 32KB
    float*          gpart  = (float*)         alloc((size_t)GM * D * 4);     // 200KB
    (void)ws_size; (void)in_sizes; (void)n_in; (void)out_size;

    const int* col = ei + E;

    // Phase A: histograms + ranks + W transposes (one dispatch)
    k_hist<<<HB + 32, 1024, 0, stream>>>(col, hist, rank, W1, W2, Wt1, Wt2);
    // Phase B: per-node prefix (register-staged 4-quarter scan); deg/dinv
    k_colscan<<<(HWRD + 63) / 64, 256, 0, stream>>>(hist, deg, dinv);
    // Phase C: parallel scatter (2/3) + MFMA gemm layer 1 (1/3) -> fp8 rows
    k_fuse<<<GF, 256, 0, stream>>>(ei, hist, rank, csr, x, Wt1, dinv, hs8);

    k_agg1<<<NW, 256, 0, stream>>>(hs8, deg, csr, b1, dinv, s18);
    k_agg2p<<<NW, 256, 0, stream>>>(s18, deg, csr, aact);
    k_gemmpool<<<GM, 256, 0, stream>>>(aact, Wt2, b2, gpart);
    k_final<<<1, 512, 0, stream>>>(gpart, Wc, bc, out);
}

// Round 9
// 205.560 us; speedup vs baseline: 1.0382x; 1.0186x over previous
//
#include <hip/hip_runtime.h>
#include <hip/hip_fp16.h>

// GCN: h1 = relu(Agg(x@W1)+b1); h2 = relu(Agg(h1@W2)+b2); out = mean(h2)@Wc+bc
// norm(r,c)=dinv[r]*dinv[c] factors: GEMM epilogue prescales rows by dinv[r],
// agg sums rows, scales by dinv[c] at the end.
// R1-R13: zero-atomic CSR + MFMA gemms + fp8 gather rows (210).
// R14/R15: agg+gemm fusion dead (agg tolerates zero added work).
// R16: pk_add (208.6). R17: half-row two-pass dead (FETCH unchanged).
// R18: fp8 hact + reg-staged colscan (206.96) <= BEST, this build.
// R19: wide-issue gather dead (213.4). R20: gemm2/agg2 linearity swap +
//      pool kill = 209.4 (noise-neutral). R21: int4 s1 rows FAILED accuracy
//      (6.8e-3 > 2.7e-3): 15 levels too coarse; correlated quant bias does
//      not mean-pool away. fp8 is the precision floor for gathered rows.
// R22: revert to R18 exactly. Aggs are at a scattered-miss concurrency floor
//      (~33us/pass, 70% L2 hit, L3-latency-bound, no saturated pipe); six
//      agg theories tested, only fp8-rows ever moved it.

typedef _Float16 half8 __attribute__((ext_vector_type(8)));
typedef float f32x4 __attribute__((ext_vector_type(4)));
typedef float f32x2 __attribute__((ext_vector_type(2)));

constexpr int N = 50000;
constexpr int E = 800000;
constexpr int D = 128;
constexpr int DOUT = 40;
constexpr int CAP = 64;               // slots/node (Poisson(16) tail ~1e-18)
constexpr int HB = 128;               // histogram chunks
constexpr int EPB = E / HB;           // 6250 edges/chunk
constexpr int HWRD = 12500;           // 50000 bytes = 12500 words
constexpr int GM = (N + 127) / 128;   // 391 gemm blocks
constexpr int NW = N / 4;             // 12500 agg blocks
constexpr int GF = 3 * GM;            // 1173 = 782 scatter + 391 gemm

// ---------------- Phase A: chunk histograms + per-edge rank + W transpose ---
__global__ __launch_bounds__(1024) void k_hist(const int* __restrict__ col,
                                               unsigned char* __restrict__ hist,
                                               unsigned char* __restrict__ rank,
                                               const float* __restrict__ W1,
                                               const float* __restrict__ W2,
                                               __half* __restrict__ T1,
                                               __half* __restrict__ T2) {
    __shared__ unsigned int h[HWRD];
    int b = blockIdx.x, t = threadIdx.x;
    if (b >= HB) {                        // 32 spare blocks: Wt[n][k]=fp16(W[k][n])
        int o = (b - HB) * 1024 + t;      // 0..32767
        const float* W = (o < 16384) ? W1 : W2;
        __half* T = (o < 16384) ? T1 : T2;
        int oo = o & 16383;
        int n = oo >> 7, k = oo & 127;
        T[oo] = (__half)W[k * 128 + n];
        return;
    }
    for (int i = t; i < HWRD; i += 1024) h[i] = 0;
    __syncthreads();
    int e0 = b * EPB;
    for (int e = e0 + t; e < e0 + EPB; e += 1024) {
        int c = col[e];
        unsigned int old = atomicAdd(&h[c >> 2], 1u << ((c & 3) * 8));
        rank[e] = (unsigned char)((old >> ((c & 3) * 8)) & 0xff);
    }
    __syncthreads();
    unsigned int* out = (unsigned int*)(hist + (size_t)b * 50000);
    for (int i = t; i < HWRD; i += 1024) out[i] = h[i];
}

// ---------------- Phase B: per-node prefix over chunks; deg + dinv ---------
// SWAR dwords (4 nodes/word, deg<=255 so no cross-byte carry). 4 threads per
// column, each scans 32 chunks into registers; LDS-combine quarter sums; then
// write back exclusive prefixes. Chain depth 32 (was 128), 4x the waves.
__global__ __launch_bounds__(256) void k_colscan(unsigned char* __restrict__ hist,
                                                 int* __restrict__ deg,
                                                 float* __restrict__ dinv) {
    __shared__ unsigned int part[4][64];
    unsigned int* hw = (unsigned int*)hist;
    int c4 = blockIdx.x * 64 + (threadIdx.x & 63);
    int qq = threadIdx.x >> 6;            // chunk quarter 0..3
    bool ok = c4 < HWRD;
    unsigned int v[32];
    unsigned int s = 0;
    if (ok) {
#pragma unroll
        for (int i = 0; i < 32; ++i) v[i] = hw[(size_t)(qq * 32 + i) * HWRD + c4];
#pragma unroll
        for (int i = 0; i < 32; ++i) s += v[i];
    }
    part[qq][threadIdx.x & 63] = s;
    __syncthreads();
    unsigned int base = 0;
    for (int k = 0; k < qq; ++k) base += part[k][threadIdx.x & 63];
    if (ok) {
        unsigned int run = base;
#pragma unroll
        for (int i = 0; i < 32; ++i) {
            hw[(size_t)(qq * 32 + i) * HWRD + c4] = run;   // exclusive prefix
            run += v[i];
        }
        if (qq == 3) {                    // run == total SWAR degree
#pragma unroll
            for (int j = 0; j < 4; ++j) {
                int dg = (run >> (8 * j)) & 0xff;
                deg[4 * c4 + j] = dg;
                dinv[4 * c4 + j] = rsqrtf((float)(dg + 1));   // +1 self loop
            }
        }
    }
}

// ---------------- fp8 helpers (OCP e4m3 on gfx950) ----------------
__device__ __forceinline__ unsigned char f8enc(float v) {
    return (unsigned char)(__builtin_amdgcn_cvt_pk_fp8_f32(v, v, 0, false) & 0xff);
}
// packed: 4 cvt + 4 v_pk_add_f32 per 8 bytes
__device__ __forceinline__ void add8f8(f32x2* a, uint2 u) {
    a[0] += __builtin_amdgcn_cvt_pk_f32_fp8(u.x, false);
    a[1] += __builtin_amdgcn_cvt_pk_f32_fp8(u.x, true);
    a[2] += __builtin_amdgcn_cvt_pk_f32_fp8(u.y, false);
    a[3] += __builtin_amdgcn_cvt_pk_f32_fp8(u.y, true);
}

// ---------------- MFMA GEMM: out8[r] = fp8(dinv[r] * (A[r] @ W)) -----------
__device__ __forceinline__ half8 ldA(const float* rowp, int koff) {
    float4 u0 = *(const float4*)(rowp + koff);
    float4 u1 = *(const float4*)(rowp + koff + 4);
    half8 r;
    r[0] = (_Float16)u0.x; r[1] = (_Float16)u0.y;
    r[2] = (_Float16)u0.z; r[3] = (_Float16)u0.w;
    r[4] = (_Float16)u1.x; r[5] = (_Float16)u1.y;
    r[6] = (_Float16)u1.z; r[7] = (_Float16)u1.w;
    return r;
}
// fp8 A rows: decode 8 bytes -> 8 halves (fp8 subset of fp16: exact)
__device__ __forceinline__ half8 ldA(const unsigned char* rowp, int koff) {
    uint2 u = *(const uint2*)(rowp + koff);
    f32x2 f0 = __builtin_amdgcn_cvt_pk_f32_fp8(u.x, false);
    f32x2 f1 = __builtin_amdgcn_cvt_pk_f32_fp8(u.x, true);
    f32x2 f2 = __builtin_amdgcn_cvt_pk_f32_fp8(u.y, false);
    f32x2 f3 = __builtin_amdgcn_cvt_pk_f32_fp8(u.y, true);
    half8 r;
    r[0] = (_Float16)f0[0]; r[1] = (_Float16)f0[1];
    r[2] = (_Float16)f1[0]; r[3] = (_Float16)f1[1];
    r[4] = (_Float16)f2[0]; r[5] = (_Float16)f2[1];
    r[6] = (_Float16)f3[0]; r[7] = (_Float16)f3[1];
    return r;
}

template <typename TA>
__device__ __forceinline__ void mfma_gemm(const TA* __restrict__ A,
                                          const __half* __restrict__ Wt,
                                          const float* __restrict__ dinv,
                                          unsigned char* __restrict__ out8,
                                          int row0, int tid) {
    int wave = tid >> 6, lane = tid & 63;
    int quad = lane >> 4, c16 = lane & 15;
    int m0 = row0 + wave * 32;
    int ra = m0 + c16;      if (ra >= N) ra = 0;   // OOB rows: dummy read row 0
    int rb = m0 + 16 + c16; if (rb >= N) rb = 0;
    const TA* pa = A + (size_t)ra * D;
    const TA* pb = A + (size_t)rb * D;

    f32x4 acc[2][8];
#pragma unroll
    for (int i = 0; i < 2; ++i)
#pragma unroll
        for (int j = 0; j < 8; ++j) acc[i][j] = (f32x4){0.f, 0.f, 0.f, 0.f};

#pragma unroll
    for (int kq = 0; kq < 4; ++kq) {
        int koff = kq * 32 + quad * 8;
        half8 a0 = ldA(pa, koff);
        half8 a1 = ldA(pb, koff);
#pragma unroll
        for (int nt = 0; nt < 8; ++nt) {
            half8 bf = *(const half8*)(Wt + (size_t)(nt * 16 + c16) * D + koff);
            acc[0][nt] = __builtin_amdgcn_mfma_f32_16x16x32_f16(a0, bf, acc[0][nt], 0, 0, 0);
            acc[1][nt] = __builtin_amdgcn_mfma_f32_16x16x32_f16(a1, bf, acc[1][nt], 0, 0, 0);
        }
    }

    // C/D: col = lane&15, row = quad*4 + reg
#pragma unroll
    for (int rt = 0; rt < 2; ++rt) {
        int mt = m0 + rt * 16;
#pragma unroll
        for (int i = 0; i < 4; ++i) {
            int grow = mt + quad * 4 + i;
            if (grow < N) {
                float s = dinv[grow];
                unsigned char* orow = out8 + (size_t)grow * D + c16;
#pragma unroll
                for (int nt = 0; nt < 8; ++nt)
                    orow[nt * 16] = f8enc(acc[rt][nt][i] * s);
            }
        }
    }
}

// ---------------- Phase C fused: parallel rank-scatter + GEMM-1 -------------
__global__ __launch_bounds__(256) void k_fuse(const int* __restrict__ ei,
                                              const unsigned char* __restrict__ hist,
                                              const unsigned char* __restrict__ rank,
                                              unsigned short* __restrict__ csr,
                                              const float* __restrict__ x,
                                              const __half* __restrict__ Wt1,
                                              const float* __restrict__ dinv,
                                              unsigned char* __restrict__ out8) {
    int b = blockIdx.x, m = b % 3;
    if (m < 2) {
        // ---- scatter: 4 consecutive edges/thread, vector loads ----
        int sb = (b / 3) * 2 + m;                 // 0..781
        int e0 = sb * 1024 + threadIdx.x * 4;
        if (e0 >= E) return;
        int4 rr = *(const int4*)(ei + e0);
        int4 cc = *(const int4*)(ei + E + e0);
        uchar4 kk = *(const uchar4*)(rank + e0);
        int rs[4] = {rr.x, rr.y, rr.z, rr.w};
        int cs[4] = {cc.x, cc.y, cc.z, cc.w};
        int ks[4] = {kk.x, kk.y, kk.z, kk.w};
#pragma unroll
        for (int i = 0; i < 4; ++i) {
            int e = e0 + i;
            int c = cs[i];
            int chunk = e / EPB;
            int slot = (int)hist[(size_t)chunk * 50000 + c] + ks[i];
            if (slot < CAP) csr[(c << 6) + slot] = (unsigned short)rs[i];
        }
        return;
    }
    // ---- gemm branch ----
    mfma_gemm<float>(x, Wt1, dinv, out8, (b / 3) * 128, threadIdx.x);
}

// ---------------- Aggregation core (1 wave/node, fp8 row-sum, pk_add) ------
// EXACT R16 shape: 4 edges x 16 lanes x 8B, 4 accumulator sets, shfl 16/32.
__device__ __forceinline__ float agg_core(int c, int lane,
                                          const unsigned char* __restrict__ hs8,
                                          const int* __restrict__ deg,
                                          const unsigned short* __restrict__ csr,
                                          float* __restrict__ a0out) {
    int qw = lane >> 4;         // 0..3: edge within group of 4
    int q  = lane & 15;         // column group: bytes q*8..q*8+7
    int dgRaw = deg[c];
    int dg = dgRaw < CAP ? dgRaw : CAP;
    float dc = rsqrtf((float)(dgRaw + 1));
    int e0 = c << 6;

    f32x2 a0[4], a1[4], a2[4], a3[4];
#pragma unroll
    for (int i = 0; i < 4; ++i) {
        a0[i] = (f32x2){0.f, 0.f}; a1[i] = (f32x2){0.f, 0.f};
        a2[i] = (f32x2){0.f, 0.f}; a3[i] = (f32x2){0.f, 0.f};
    }
    if (qw == 0)                // self loop (hs8[c] already = dinv[c]*h[c])
        add8f8(a0, *(const uint2*)&hs8[((unsigned)c << 7) + q * 8]);

    int j = 0;
    for (; j + 16 <= dg; j += 16) {
        int r0 = csr[e0 + j + qw];
        int r1 = csr[e0 + j + 4 + qw];
        int r2 = csr[e0 + j + 8 + qw];
        int r3 = csr[e0 + j + 12 + qw];
        uint2 u0 = *(const uint2*)&hs8[((unsigned)r0 << 7) + q * 8];
        uint2 u1 = *(const uint2*)&hs8[((unsigned)r1 << 7) + q * 8];
        uint2 u2 = *(const uint2*)&hs8[((unsigned)r2 << 7) + q * 8];
        uint2 u3 = *(const uint2*)&hs8[((unsigned)r3 << 7) + q * 8];
        add8f8(a0, u0); add8f8(a1, u1); add8f8(a2, u2); add8f8(a3, u3);
    }
    if (j + 8 <= dg) {
        int r0 = csr[e0 + j + qw];
        int r1 = csr[e0 + j + 4 + qw];
        uint2 u0 = *(const uint2*)&hs8[((unsigned)r0 << 7) + q * 8];
        uint2 u1 = *(const uint2*)&hs8[((unsigned)r1 << 7) + q * 8];
        add8f8(a0, u0); add8f8(a1, u1);
        j += 8;
    }
    if (j + 4 <= dg) {
        int r0 = csr[e0 + j + qw];
        add8f8(a0, *(const uint2*)&hs8[((unsigned)r0 << 7) + q * 8]);
        j += 4;
    }
    int rem = dg - j;                     // 0..3
    if (qw < rem) {
        int r0 = csr[e0 + j + qw];
        add8f8(a1, *(const uint2*)&hs8[((unsigned)r0 << 7) + q * 8]);
    }

#pragma unroll
    for (int i = 0; i < 4; ++i) { a0[i] += a1[i]; a2[i] += a3[i]; a0[i] += a2[i]; }
#pragma unroll
    for (int t = 0; t < 8; ++t) {
        float v = a0[t >> 1][t & 1];
        v += __shfl_xor(v, 16, 64);
        v += __shfl_xor(v, 32, 64);
        a0out[t] = v;
    }
    return dc;
}

// layer-1 agg: writes fp8 h1 rows (gemm2 decodes fp8->fp16; halves hact traffic)
__global__ __launch_bounds__(256) void k_agg1(const unsigned char* __restrict__ hs8,
                                              const int* __restrict__ deg,
                                              const unsigned short* __restrict__ csr,
                                              const float* __restrict__ bias,
                                              unsigned char* __restrict__ out8) {
    int wave = threadIdx.x >> 6;
    int lane = threadIdx.x & 63;
    int c = blockIdx.x * 4 + wave;
    float a0[8];
    float dc = agg_core(c, lane, hs8, deg, csr, a0);
    if ((lane >> 4) == 0) {
        int q = lane & 15;
        union { unsigned char b[8]; uint2 u; } p;
#pragma unroll
        for (int i = 0; i < 8; ++i)
            p.b[i] = f8enc(fmaxf(fmaf(dc, a0[i], bias[q * 8 + i]), 0.f));
        *(uint2*)&out8[((unsigned)c << 7) + q * 8] = p.u;
    }
}

// ---------------- GEMM layer 2 (fp8 A -> fp8 out) ----------------
__global__ __launch_bounds__(256) void k_gemm(const unsigned char* __restrict__ A,
                                              const __half* __restrict__ Wt,
                                              const float* __restrict__ dinv,
                                              unsigned char* __restrict__ out8) {
    mfma_gemm<unsigned char>(A, Wt, dinv, out8, blockIdx.x * 128, threadIdx.x);
}

// layer-2 agg: reduces h2 rows straight into per-block pool partials
__global__ __launch_bounds__(256) void k_agg2(const unsigned char* __restrict__ hs8,
                                              const int* __restrict__ deg,
                                              const unsigned short* __restrict__ csr,
                                              const float* __restrict__ bias,
                                              float* __restrict__ gpart) {
    __shared__ float gblk[4][128];
    int wave = threadIdx.x >> 6;
    int lane = threadIdx.x & 63;
    int c = blockIdx.x * 4 + wave;
    float a0[8];
    float dc = agg_core(c, lane, hs8, deg, csr, a0);
    if ((lane >> 4) == 0) {
        int q = lane & 15;
#pragma unroll
        for (int i = 0; i < 8; ++i)
            gblk[wave][q * 8 + i] = fmaxf(fmaf(dc, a0[i], bias[q * 8 + i]), 0.f);
    }
    __syncthreads();
    int t = threadIdx.x;
    if (t < 128)
        gpart[(size_t)blockIdx.x * 128 + t] =
            gblk[0][t] + gblk[1][t] + gblk[2][t] + gblk[3][t];
}

// ---------------- Pool stage 2: 12500 partials -> 256 partials --------------
__global__ __launch_bounds__(256) void k_pool(const float* __restrict__ gpart,
                                              float* __restrict__ gpart2) {
    int d = threadIdx.x & 127;
    int half = threadIdx.x >> 7;
    int b = blockIdx.x;                 // 256 blocks
    int per = (NW + 255) / 256;         // 49
    int r0 = b * per;
    int r1 = r0 + per;
    if (r1 > NW) r1 = NW;
    float acc = 0.f;
    for (int r = r0 + half; r < r1; r += 2)
        acc += gpart[(size_t)r * D + d];
    __shared__ float red[256];
    red[threadIdx.x] = acc;
    __syncthreads();
    if (half == 0) gpart2[(size_t)b * D + d] = red[d] + red[128 + d];
}

// ---------------- Final: g = sum(gpart2)/N; out = g@Wc + bc ----------------
__global__ __launch_bounds__(512) void k_final(const float* __restrict__ gpart2,
                                               const float* __restrict__ Wc,
                                               const float* __restrict__ bc,
                                               float* __restrict__ out) {
    __shared__ float g[D];
    __shared__ float red[512];
    int t = threadIdx.x;
    int d = t & 127, grp = t >> 7;
    float s = 0.f;
#pragma unroll 4
    for (int w = grp * 64; w < grp * 64 + 64; ++w)
        s += gpart2[(size_t)w * D + d];
    red[t] = s;
    __syncthreads();
    if (grp == 0)
        g[d] = (red[d] + red[128 + d] + red[256 + d] + red[384 + d]) * (1.0f / (float)N);
    __syncthreads();
    if (t < DOUT) {
        float acc = bc[t];
        for (int dd = 0; dd < D; ++dd) acc = fmaf(g[dd], Wc[dd * DOUT + t], acc);
        out[t] = acc;
    }
}

extern "C" void kernel_launch(void* const* d_in, const int* in_sizes, int n_in,
                              void* d_out, int out_size, void* d_ws, size_t ws_size,
                              hipStream_t stream) {
    const float* x  = (const float*)d_in[0];
    const int*   ei = (const int*)d_in[1];
    const float* W1 = (const float*)d_in[2];
    const float* b1 = (const float*)d_in[3];
    const float* W2 = (const float*)d_in[4];
    const float* b2 = (const float*)d_in[5];
    const float* Wc = (const float*)d_in[6];
    const float* bc = (const float*)d_in[7];
    float* out = (float*)d_out;

    char* ws = (char*)d_ws;
    size_t off = 0;
    auto alloc = [&](size_t bytes) {
        void* p = ws + off;
        off += (bytes + 511) & ~(size_t)511;
        return p;
    };
    unsigned char*  hist   = (unsigned char*) alloc((size_t)HB * 50000);     // 6.4MB
    unsigned char*  rank   = (unsigned char*) alloc((size_t)E);              // 0.8MB
    int*            deg    = (int*)           alloc((size_t)N * 4);
    float*          dinv   = (float*)         alloc((size_t)N * 4);
    unsigned short* csr    = (unsigned short*)alloc((size_t)N * CAP * 2);    // 6.4MB
    unsigned char*  hs8    = (unsigned char*) alloc((size_t)N * D);          // 6.4MB
    unsigned char*  h18    = (unsigned char*) alloc((size_t)N * D);          // 6.4MB (fp8 h1 act)
    __half*         Wt1    = (__half*)        alloc((size_t)D * D * 2);      // 32KB
    __half*         Wt2    = (__half*)        alloc((size_t)D * D * 2);      // 32KB
    float*          gpart  = (float*)         alloc((size_t)NW * D * 4);     // 6.4MB
    float*          gpart2 = (float*)         alloc((size_t)256 * D * 4);
    (void)ws_size; (void)in_sizes; (void)n_in; (void)out_size;

    const int* col = ei + E;

    // Phase A: histograms + ranks + W transposes (one dispatch)
    k_hist<<<HB + 32, 1024, 0, stream>>>(col, hist, rank, W1, W2, Wt1, Wt2);
    // Phase B: per-node prefix (register-staged 4-quarter scan); deg/dinv
    k_colscan<<<(HWRD + 63) / 64, 256, 0, stream>>>(hist, deg, dinv);
    // Phase C: parallel scatter (2/3) + MFMA gemm layer 1 (1/3) -> fp8 rows
    k_fuse<<<GF, 256, 0, stream>>>(ei, hist, rank, csr, x, Wt1, dinv, hs8);

    k_agg1<<<NW, 256, 0, stream>>>(hs8, deg, csr, b1, h18);
    k_gemm<<<GM, 256, 0, stream>>>(h18, Wt2, dinv, hs8);
    k_agg2<<<NW, 256, 0, stream>>>(hs8, deg, csr, b2, gpart);
    k_pool<<<256, 256, 0, stream>>>(gpart, gpart2);
    k_final<<<1, 512, 0, stream>>>(gpart2, Wc, bc, out);
}